// Round 3
// baseline (195.718 us; speedup 1.0000x reference)
//
#include <hip/hip_runtime.h>

// PointGatedBlock: SE3 point conv + gated nonlinearity. ALL fp32 in/out
// (per reference dtypes); bf16 only internally for MFMA operands.
// B=4, N=M=1024, DIM_IN=104, DIM_OUT=144 (=120 feats + 24 gates), 16 radial basis.
//
// Fused single kernel: grid 256 = (b, 16-n tile); block 512 (8 waves).
//  stage:   phi[(n,k)=256][64 m] bf16 in LDS (fp32 radial basis * mask, cvt->bf16)
//           featT[i][64 m] bf16 in LDS (fp32 load, cvt->bf16)
//  GEMM1:   tmp[(n,k), i] += phi . featT   (mfma_f32_16x16x32_bf16, 4x4 tiles/wave)
//  GEMM2:   y[o, n] = sum_{k,i} W[k,o,i] * tmp[n,k,i]; A-frags from global fp32 W
//           (8-elem ki blocks never straddle k because 104 % 8 == 0), cvt->bf16
//  epilogue: relu (o<32), y*sigmoid(gate) for l=1 (o in [32,80)) / l=2 ([80,120)),
//           fp32 stores.
// diff/mask registers are preloaded one m-tile ahead so HBM latency overlaps GEMM1.

typedef __attribute__((ext_vector_type(4))) float f32x4;
typedef __attribute__((ext_vector_type(8))) short s16x8;
typedef __attribute__((ext_vector_type(4))) unsigned short u16x4;

#define NN 1024
#define MM 1024
#define DI 104
#define DO 144
#define NBASIS 16
#define MT 64
#define PHI_STRIDE 72      // 64 + 8 pad: rows 16B-aligned, ~2-way banks (free)
#define FEAT_STRIDE 72
#define TT_STRIDE 1672     // 16*104 + 8 pad
#define YST 17

#define SMEM_FEAT 36864            // after phi: 256*72*2
#define SMEM_Y    55296            // after featT (128 rows): 36864 + 128*72*2
#define SMEM_TOTAL (55296 + 144*17*4)   // + ylds = 65088 B

__device__ __forceinline__ unsigned short f2b(float f) {
    unsigned int x = __builtin_bit_cast(unsigned int, f);
    x += 0x7fffu + ((x >> 16) & 1u);
    return (unsigned short)(x >> 16);
}

__device__ __forceinline__ s16x8 cvt8(const float* __restrict__ p) {
    f32x4 a = *(const f32x4*)p;
    f32x4 b = *(const f32x4*)(p + 4);
    s16x8 r;
    r[0]=(short)f2b(a[0]); r[1]=(short)f2b(a[1]); r[2]=(short)f2b(a[2]); r[3]=(short)f2b(a[3]);
    r[4]=(short)f2b(b[0]); r[5]=(short)f2b(b[1]); r[6]=(short)f2b(b[2]); r[7]=(short)f2b(b[3]);
    return r;
}

__global__ __launch_bounds__(512, 2)
void pgb_kernel(const float* __restrict__ feat_g,
                const float* __restrict__ diff_g,
                const float* __restrict__ mask_g,
                const float* __restrict__ W_g,
                float* __restrict__ out_g)
{
    __shared__ __align__(16) unsigned char smem[SMEM_TOTAL];
    unsigned short* phi   = (unsigned short*)(smem);
    unsigned short* featT = (unsigned short*)(smem + SMEM_FEAT);
    unsigned short* Tt    = (unsigned short*)(smem);          // aliases phi (after barrier)
    float*          ylds  = (float*)(smem + SMEM_Y);

    const int t    = threadIdx.x;
    const int b    = blockIdx.x >> 6;
    const int n0   = (blockIdx.x & 63) << 4;
    const int wave = t >> 6;
    const int lane = t & 63;
    const int l15  = lane & 15;
    const int q    = lane >> 4;
    const int wr   = wave >> 1;          // rowtile group (4 rowtiles each)
    const int ct0  = (wave & 1) << 2;    // coltile base 0 or 4

    // zero featT pad rows 104..127 (read by the discarded col-tiles)
    for (int u = t; u < (24*FEAT_STRIDE)/2; u += 512)
        ((unsigned int*)(featT + DI*FEAT_STRIDE))[u] = 0u;

    f32x4 acc[4][4];
#pragma unroll
    for (int rr = 0; rr < 4; ++rr)
#pragma unroll
        for (int cc = 0; cc < 4; ++cc)
            acc[rr][cc] = (f32x4){0.f, 0.f, 0.f, 0.f};

    const int pn = t >> 5;               // n row 0..15
    const int pm = (t & 31) << 1;        // m pair base (even)
    const float CEXP = -23.083120654223414f;   // -GAMMA * log2(e)
    const size_t dmrow = (size_t)(b*NN + n0 + pn) * MM;

    // preload m-tile 0 diff/mask (fp32)
    float dx0, dy0, dz0, dx1, dy1, dz1, mk0, mk1;
    {
        const float* dp = diff_g + (dmrow + pm)*3;
        dx0=dp[0]; dy0=dp[1]; dz0=dp[2]; dx1=dp[3]; dy1=dp[4]; dz1=dp[5];
        const float* mp = mask_g + dmrow + pm;
        mk0=mp[0]; mk1=mp[1];
    }

    for (int s = 0; s < MM/MT; ++s) {
        const int ms = s * MT;
        // issue next tile's diff/mask loads early (consumed after GEMM1)
        float nx0=0, ny0=0, nz0=0, nx1=0, ny1=0, nz1=0, nm0=0, nm1=0;
        if (s + 1 < MM/MT) {
            const float* dp = diff_g + (dmrow + ms + MT + pm)*3;
            nx0=dp[0]; ny0=dp[1]; nz0=dp[2]; nx1=dp[3]; ny1=dp[4]; nz1=dp[5];
            const float* mp = mask_g + dmrow + ms + MT + pm;
            nm0=mp[0]; nm1=mp[1];
        }
        // ---- phi: 1 n x 2 consecutive m per thread, all 16 k ----
        {
            float r0 = sqrtf(dx0*dx0 + dy0*dy0 + dz0*dz0 + 1e-12f);
            float r1 = sqrtf(dx1*dx1 + dy1*dy1 + dz1*dz1 + 1e-12f);
#pragma unroll
            for (int k = 0; k < NBASIS; ++k) {
                float ck = (float)k * (2.0f/15.0f);
                float d0 = r0 - ck, d1 = r1 - ck;
                float p0 = exp2f(CEXP*d0*d0) * mk0;
                float p1 = exp2f(CEXP*d1*d1) * mk1;
                unsigned int pk = (unsigned int)f2b(p0) | ((unsigned int)f2b(p1) << 16);
                *(unsigned int*)(phi + (pn*NBASIS + k)*PHI_STRIDE + pm) = pk;
            }
        }
        // ---- stage featT: 104 rows x 64 m, fp32 load -> bf16 store ----
        for (int u = t; u < 1664; u += 512) {
            int fi = u >> 4, part = (u & 15) << 2;
            f32x4 v = *(const f32x4*)(feat_g + (((size_t)(b*DI + fi)) << 10) + ms + part);
            u16x4 h;
            h[0]=f2b(v[0]); h[1]=f2b(v[1]); h[2]=f2b(v[2]); h[3]=f2b(v[3]);
            *(u16x4*)(featT + fi*FEAT_STRIDE + part) = h;
        }
        __syncthreads();
        // ---- GEMM1: 4x4 tiles of 16x16 per wave, K = 64 (2 x 32) ----
#pragma unroll
        for (int kk = 0; kk < 2; ++kk) {
            const int mo = kk*32 + q*8;
            s16x8 afrag[4];
#pragma unroll
            for (int rr = 0; rr < 4; ++rr)
                afrag[rr] = *(const s16x8*)(phi + ((wr*4+rr)*16 + l15)*PHI_STRIDE + mo);
#pragma unroll
            for (int cc = 0; cc < 4; ++cc) {
                s16x8 bfrag = *(const s16x8*)(featT + ((ct0+cc)*16 + l15)*FEAT_STRIDE + mo);
#pragma unroll
                for (int rr = 0; rr < 4; ++rr)
                    acc[rr][cc] = __builtin_amdgcn_mfma_f32_16x16x32_bf16(
                        afrag[rr], bfrag, acc[rr][cc], 0, 0, 0);
            }
        }
        __syncthreads();
        dx0=nx0; dy0=ny0; dz0=nz0; dx1=nx1; dy1=ny1; dz1=nz1; mk0=nm0; mk1=nm1;
    }

    // ---- tmp (C-layout: col=i in l15, row=k in q*4+r; rowtile = n) -> Tt[n][k*104+i] ----
#pragma unroll
    for (int rr = 0; rr < 4; ++rr) {
        int nloc = wr*4 + rr;
#pragma unroll
        for (int cc = 0; cc < 4; ++cc) {
            int i = (ct0+cc)*16 + l15;
            if (i < DI) {
#pragma unroll
                for (int r = 0; r < 4; ++r)
                    Tt[nloc*TT_STRIDE + (q*4+r)*DI + i] = f2b(acc[rr][cc][r]);
            }
        }
    }
    __syncthreads();

    // ---- GEMM2: y[o,n] = sum_ki W[k,o,i] * Tt[n][ki]; 52 K-steps of 32 ----
    f32x4 y0 = (f32x4){0.f,0.f,0.f,0.f}, y1 = (f32x4){0.f,0.f,0.f,0.f};
    const int o0 = wave*16 + l15;
    const int o1 = 128 + l15;      // o-tile 8, handled by wave 0
#pragma unroll 4
    for (int s3 = 0; s3 < 52; ++s3) {
        int a = s3*4 + q;          // 8-elem ki block; k = a/13, i = (a%13)*8
        int k = a / 13;
        int i = (a - k*13) << 3;
        s16x8 bfrag = *(const s16x8*)(Tt + l15*TT_STRIDE + s3*32 + q*8);
        s16x8 af0 = cvt8(W_g + (size_t)(k*DO + o0)*DI + i);
        y0 = __builtin_amdgcn_mfma_f32_16x16x32_bf16(af0, bfrag, y0, 0, 0, 0);
        if (wave == 0) {
            s16x8 af1 = cvt8(W_g + (size_t)(k*DO + o1)*DI + i);
            y1 = __builtin_amdgcn_mfma_f32_16x16x32_bf16(af1, bfrag, y1, 0, 0, 0);
        }
    }
#pragma unroll
    for (int r = 0; r < 4; ++r)
        ylds[(wave*16 + q*4 + r)*YST + l15] = y0[r];
    if (wave == 0) {
#pragma unroll
        for (int r = 0; r < 4; ++r)
            ylds[(128 + q*4 + r)*YST + l15] = y1[r];
    }
    __syncthreads();

    // ---- gating epilogue: out[b, o(<120), n0+n] fp32 ----
    for (int idx = t; idx < 120*16; idx += 512) {
        int o = idx >> 4, nn = idx & 15;
        float y = ylds[o*YST + nn];
        float v;
        if (o < 32) {
            v = fmaxf(y, 0.f);
        } else if (o < 80) {
            float g = ylds[(120 + (o-32)/3)*YST + nn];
            v = y / (1.f + __expf(-g));
        } else {
            float g = ylds[(136 + (o-80)/5)*YST + nn];
            v = y / (1.f + __expf(-g));
        }
        out_g[((size_t)(b*120 + o) << 10) + n0 + nn] = v;
    }
}

extern "C" void kernel_launch(void* const* d_in, const int* in_sizes, int n_in,
                              void* d_out, int out_size, void* d_ws, size_t ws_size,
                              hipStream_t stream) {
    const float* feat = (const float*)d_in[0];  // [4,104,1024] fp32
    const float* diff = (const float*)d_in[1];  // [4,1024,1024,3] fp32
    const float* mask = (const float*)d_in[2];  // [4,1024,1024] fp32
    const float* W    = (const float*)d_in[3];  // [16,144,104] fp32
    float* out = (float*)d_out;                 // [4,120,1024] fp32
    (void)in_sizes; (void)n_in; (void)out_size; (void)d_ws; (void)ws_size;
    pgb_kernel<<<dim3(256), dim3(512), 0, stream>>>(feat, diff, mask, W, out);
}

// Round 4
// 177.180 us; speedup vs baseline: 1.1046x; 1.1046x over previous
//
#include <hip/hip_runtime.h>

// PointGatedBlock: SE3 point conv + gated nonlinearity. fp32 in/out,
// bf16 internally for MFMA operands. B=4, N=M=1024, DIM_IN=104, DIM_OUT=144.
//
// R4: occupancy + VALU attack. grid 512 = (b, 8-n tile); block 512 (8 waves);
// LDS 74.8 KB -> 2 blocks/CU (16 waves). m-loop: 8 iters of MT=128.
//  phi[(n,k)=128 rows][128 m] bf16: log-space recurrence, 2 exp2/k-pair,
//    mask folded via +log2(mk); packed to bf16 with v_perm round-half-up.
//  featT[i=128 rows][128 m] bf16 staged from global fp32.
//  GEMM1: 2x4 wave-tiles of 16x16x32 bf16 (reads:MFMA = 0.75).
//  GEMM2: y[144 o][8 n] from global W (fp32->bf16), Tt in LDS.
//  epilogue: relu / y*sigmoid(gate), fp32 out.

typedef __attribute__((ext_vector_type(4))) float f32x4;
typedef __attribute__((ext_vector_type(8))) short s16x8;

#define DI 104
#define DO 144
#define MT 128
#define PST 136            // phi/featT row stride (elems)
#define TTST 1688          // Tt row stride: 1664 + 24 pad
#define YST 9

#define SMEM_FEAT 34816                 // phi: 128*136*2
#define SMEM_Y    69632                 // featT: +128*136*2
#define SMEM_TOTAL (69632 + 144*9*4)    // + ylds = 74816 B

__device__ __forceinline__ float fexp2(float x) {
#if __has_builtin(__builtin_amdgcn_exp2f)
    return __builtin_amdgcn_exp2f(x);
#else
    return exp2f(x);
#endif
}
__device__ __forceinline__ float flog2(float x) {
#if __has_builtin(__builtin_amdgcn_logf)
    return __builtin_amdgcn_logf(x);
#else
    return log2f(x);
#endif
}
__device__ __forceinline__ float fsqrt_(float x) {
#if __has_builtin(__builtin_amdgcn_sqrtf)
    return __builtin_amdgcn_sqrtf(x);
#else
    return sqrtf(x);
#endif
}
__device__ __forceinline__ float frcp_(float x) {
#if __has_builtin(__builtin_amdgcn_rcpf)
    return __builtin_amdgcn_rcpf(x);
#else
    return 1.0f / x;
#endif
}
// pack two fp32 -> bf16x2 (round-half-up) in 3 VALU ops
__device__ __forceinline__ unsigned int pkbf(float lo, float hi) {
    unsigned int a = __builtin_bit_cast(unsigned int, lo) + 0x8000u;
    unsigned int b = __builtin_bit_cast(unsigned int, hi) + 0x8000u;
    return __builtin_amdgcn_perm(b, a, 0x07060302u);
}
__device__ __forceinline__ unsigned short f2b(float f) {
    return (unsigned short)((__builtin_bit_cast(unsigned int, f) + 0x8000u) >> 16);
}

__global__ __launch_bounds__(512, 4)
void pgb_kernel(const float* __restrict__ feat_g,
                const float* __restrict__ diff_g,
                const float* __restrict__ mask_g,
                const float* __restrict__ W_g,
                float* __restrict__ out_g)
{
    __shared__ __align__(16) unsigned char smem[SMEM_TOTAL];
    unsigned short* phi   = (unsigned short*)(smem);
    unsigned short* featT = (unsigned short*)(smem + SMEM_FEAT);
    unsigned short* Tt    = (unsigned short*)(smem);          // aliases phi (post-barrier)
    float*          ylds  = (float*)(smem + SMEM_Y);

    const int t    = threadIdx.x;
    const int b    = blockIdx.x >> 7;
    const int n0   = (blockIdx.x & 127) << 3;
    const int wave = t >> 6;
    const int lane = t & 63;
    const int l15  = lane & 15;
    const int q    = lane >> 4;
    const int rt0  = (wave >> 1) << 1;   // rowtile base: 0,2,4,6 (row = n*16+k)
    const int ch   = (wave & 1) << 2;    // coltile base: 0 or 4 (i-dim)

    // zero featT pad rows 104..127 (read by high coltiles)
    for (int u = t; u < (24*PST)/2; u += 512)
        ((unsigned int*)(featT + DI*PST))[u] = 0u;

    f32x4 acc[2][4];
#pragma unroll
    for (int rr = 0; rr < 2; ++rr)
#pragma unroll
        for (int cc = 0; cc < 4; ++cc)
            acc[rr][cc] = (f32x4){0.f, 0.f, 0.f, 0.f};

    const int pn = t >> 6;               // n-row 0..7
    const int pm = (t & 63) << 1;        // m pair base (even), 0..126
    const float CEXP = -23.083120654223414f;   // -GAMMA * log2(e)
    const float A1 = 6.1554988411262437f;      // -2*CEXP*DL
    const float A0 = -0.41036658940841623f;    // CEXP*DL*DL
    const float V2 = -0.82073317881683246f;    // 2*CEXP*DL*DL
    const size_t dmrow = (size_t)((b << 10) + n0 + pn) << 10;

    // preload m-tile 0 diff/mask
    float dx0, dy0, dz0, dx1, dy1, dz1, mk0, mk1;
    {
        const float* dp = diff_g + (dmrow + pm)*3;
        dx0=dp[0]; dy0=dp[1]; dz0=dp[2]; dx1=dp[3]; dy1=dp[4]; dz1=dp[5];
        const float* mp = mask_g + dmrow + pm;
        mk0=mp[0]; mk1=mp[1];
    }

    for (int s = 0; s < 1024/MT; ++s) {
        const int ms = s * MT;
        // prefetch next tile's diff/mask (drained at the barrier below, but
        // ~2K cycles of phi VALU sit between issue and drain)
        float nx0=0, ny0=0, nz0=0, nx1=0, ny1=0, nz1=0, nm0=0, nm1=0;
        if (s + 1 < 1024/MT) {
            const float* dp = diff_g + (dmrow + ms + MT + pm)*3;
            nx0=dp[0]; ny0=dp[1]; nz0=dp[2]; nx1=dp[3]; ny1=dp[4]; nz1=dp[5];
            const float* mp = mask_g + dmrow + ms + MT + pm;
            nm0=mp[0]; nm1=mp[1];
        }
        // ---- phi: log-space recurrence. E_k = CEXP*(r-k*DL)^2 + log2(mask)
        {
            float r0 = fsqrt_(dx0*dx0 + dy0*dy0 + dz0*dz0 + 1e-12f);
            float r1 = fsqrt_(dx1*dx1 + dy1*dy1 + dz1*dz1 + 1e-12f);
            float E0 = fmaf(CEXP*r0, r0, flog2(mk0));
            float E1 = fmaf(CEXP*r1, r1, flog2(mk1));
            float s0 = fmaf(A1, r0, A0);
            float s1 = fmaf(A1, r1, A0);
#pragma unroll
            for (int k = 0; k < 16; ++k) {
                float p0 = fexp2(E0);
                float p1 = fexp2(E1);
                *(unsigned int*)(phi + (pn*16 + k)*PST + pm) = pkbf(p0, p1);
                E0 += s0; s0 += V2;
                E1 += s1; s1 += V2;
            }
        }
        // ---- stage featT: 104 rows x 128 m, fp32 -> bf16 (perm-pack) ----
        for (int u = t; u < 3328; u += 512) {
            int fi = u >> 5, part = (u & 31) << 2;
            f32x4 v = *(const f32x4*)(feat_g + (((size_t)(b*DI + fi)) << 10) + ms + part);
            unsigned int lohi[2] = { pkbf(v[0], v[1]), pkbf(v[2], v[3]) };
            *(unsigned long long*)(featT + fi*PST + part) = *(unsigned long long*)lohi;
        }
        __syncthreads();
        // ---- GEMM1: 2x4 tiles of 16x16x32 per wave, K = 128 (4 x 32) ----
#pragma unroll
        for (int kk = 0; kk < 4; ++kk) {
            const int mo = kk*32 + q*8;
            s16x8 a0 = *(const s16x8*)(phi + ((rt0    )*16 + l15)*PST + mo);
            s16x8 a1 = *(const s16x8*)(phi + ((rt0 + 1)*16 + l15)*PST + mo);
#pragma unroll
            for (int cc = 0; cc < 4; ++cc) {
                s16x8 bf = *(const s16x8*)(featT + ((ch+cc)*16 + l15)*PST + mo);
                acc[0][cc] = __builtin_amdgcn_mfma_f32_16x16x32_bf16(a0, bf, acc[0][cc], 0, 0, 0);
                acc[1][cc] = __builtin_amdgcn_mfma_f32_16x16x32_bf16(a1, bf, acc[1][cc], 0, 0, 0);
            }
        }
        __syncthreads();
        dx0=nx0; dy0=ny0; dz0=nz0; dx1=nx1; dy1=ny1; dz1=nz1; mk0=nm0; mk1=nm1;
    }

    // ---- acc (C-layout: col=l15=i-part, row=q*4+r=k) -> Tt[n][k*104+i] bf16 ----
#pragma unroll
    for (int rr = 0; rr < 2; ++rr) {
        int nloc = rt0 + rr;             // row>>4 = rowtile = n-local
#pragma unroll
        for (int cc = 0; cc < 4; ++cc) {
            int i = (ch+cc)*16 + l15;
            if (i < DI) {
#pragma unroll
                for (int r = 0; r < 4; ++r)
                    Tt[nloc*TTST + (q*4+r)*DI + i] = f2b(acc[rr][cc][r]);
            }
        }
    }
    __syncthreads();

    // ---- GEMM2: y[o,n] = sum_ki W[k,o,i]*Tt[n][ki]; 52 K-steps of 32.
    // B-cols 8..15 duplicate rows 0..7 (l15&7) and are ignored at write.
    f32x4 y0 = (f32x4){0.f,0.f,0.f,0.f}, y1 = (f32x4){0.f,0.f,0.f,0.f};
    const int o0 = wave*16 + l15;
    const int o1 = 128 + l15;            // o-tile 8, handled by wave 0
#pragma unroll 4
    for (int s3 = 0; s3 < 52; ++s3) {
        int a = s3*4 + q;                // 8-elem ki block; k=a/13, i=(a%13)*8
        int k = a / 13;
        int i = (a - k*13) << 3;
        s16x8 bf = *(const s16x8*)(Tt + (l15 & 7)*TTST + s3*32 + q*8);
        const float* wp0 = W_g + (size_t)(k*DO + o0)*DI + i;
        f32x4 wa = *(const f32x4*)wp0;
        f32x4 wb = *(const f32x4*)(wp0 + 4);
        unsigned int w01[2] = { pkbf(wa[0], wa[1]), pkbf(wa[2], wa[3]) };
        unsigned int w23[2] = { pkbf(wb[0], wb[1]), pkbf(wb[2], wb[3]) };
        s16x8 af;
        *(unsigned long long*)&af      = *(unsigned long long*)w01;
        *((unsigned long long*)&af + 1)= *(unsigned long long*)w23;
        y0 = __builtin_amdgcn_mfma_f32_16x16x32_bf16(af, bf, y0, 0, 0, 0);
        if (wave == 0) {
            const float* wp1 = W_g + (size_t)(k*DO + o1)*DI + i;
            f32x4 wc = *(const f32x4*)wp1;
            f32x4 wd = *(const f32x4*)(wp1 + 4);
            unsigned int w45[2] = { pkbf(wc[0], wc[1]), pkbf(wc[2], wc[3]) };
            unsigned int w67[2] = { pkbf(wd[0], wd[1]), pkbf(wd[2], wd[3]) };
            s16x8 ag;
            *(unsigned long long*)&ag      = *(unsigned long long*)w45;
            *((unsigned long long*)&ag + 1)= *(unsigned long long*)w67;
            y1 = __builtin_amdgcn_mfma_f32_16x16x32_bf16(ag, bf, y1, 0, 0, 0);
        }
    }
    if (l15 < 8) {
#pragma unroll
        for (int r = 0; r < 4; ++r)
            ylds[(wave*16 + q*4 + r)*YST + l15] = y0[r];
        if (wave == 0) {
#pragma unroll
            for (int r = 0; r < 4; ++r)
                ylds[(128 + q*4 + r)*YST + l15] = y1[r];
        }
    }
    __syncthreads();

    // ---- gating epilogue: out[b, o(<120), n0+nn] fp32 ----
    const float L2E = 1.4426950408889634f;
    for (int idx = t; idx < 120*8; idx += 512) {
        int o = idx >> 3, nn = idx & 7;
        float y = ylds[o*YST + nn];
        float v;
        if (o < 32) {
            v = fmaxf(y, 0.f);
        } else if (o < 80) {
            float g = ylds[(120 + (o-32)/3)*YST + nn];
            v = y * frcp_(1.f + fexp2(-g*L2E));
        } else {
            float g = ylds[(136 + (o-80)/5)*YST + nn];
            v = y * frcp_(1.f + fexp2(-g*L2E));
        }
        out_g[((size_t)(b*120 + o) << 10) + n0 + nn] = v;
    }
}

extern "C" void kernel_launch(void* const* d_in, const int* in_sizes, int n_in,
                              void* d_out, int out_size, void* d_ws, size_t ws_size,
                              hipStream_t stream) {
    const float* feat = (const float*)d_in[0];  // [4,104,1024] fp32
    const float* diff = (const float*)d_in[1];  // [4,1024,1024,3] fp32
    const float* mask = (const float*)d_in[2];  // [4,1024,1024] fp32
    const float* W    = (const float*)d_in[3];  // [16,144,104] fp32
    float* out = (float*)d_out;                 // [4,120,1024] fp32
    (void)in_sizes; (void)n_in; (void)out_size; (void)d_ws; (void)ws_size;
    pgb_kernel<<<dim3(512), dim3(512), 0, stream>>>(feat, diff, mask, W, out);
}

// Round 5
// 142.381 us; speedup vs baseline: 1.3746x; 1.2444x over previous
//
#include <hip/hip_runtime.h>

// PointGatedBlock: SE3 point conv + gated nonlinearity. fp32 in/out.
// R5: pre-convert W+feat to bf16 in d_ws (once per launch, tiny kernel);
// main kernel: grid 512 = (b, 8-n); block 512 (8 waves); LDS double-buffered
// phi+feat -> ONE barrier per m-iter; diff/feat register prefetch 1 tile ahead.
//  phi[(n,k)=128 rows][64 m] bf16 (log-space recurrence, 2 exp2 per k-pair)
//  feat[112 rows][64 m] bf16 staged from pre-converted ws (rows 104..111 zero)
//  GEMM1: waves = 4 rowgroups x 2 colgroups; 2 rowtiles x 4|3 coltiles each.
//  GEMM2: y[144 o][8 n]; A-frags = bf16 W from ws (no per-block conversion).
//  epilogue: relu / y*sigmoid(gate), fp32 out.

typedef __attribute__((ext_vector_type(4))) float f32x4;
typedef __attribute__((ext_vector_type(8))) short s16x8;

#define DI 104
#define DO 144
#define MT 64
#define PST 72             // phi/feat row stride (elems); 144 B rows -> 4-bank skew
#define TTST 1688          // Tt row stride: 1664 + 24 pad
#define YST 9

#define W_ELEMS 239616     // 16*144*104
#define F_ELEMS 425984     // 4*104*1024

// LDS byte offsets
#define OFF_PHI0 0
#define OFF_PHI1 18432                  // 128*72*2
#define OFF_FEAT0 36864
#define OFF_FEAT1 52992                 // + 112*72*2 = 16128
#define OFF_Y 69120
#define SMEM_TOTAL (69120 + 144*9*4)    // 74304 B -> 2 blocks/CU

__device__ __forceinline__ float fexp2(float x) {
#if __has_builtin(__builtin_amdgcn_exp2f)
    return __builtin_amdgcn_exp2f(x);
#else
    return exp2f(x);
#endif
}
__device__ __forceinline__ float flog2(float x) {
#if __has_builtin(__builtin_amdgcn_logf)
    return __builtin_amdgcn_logf(x);
#else
    return log2f(x);
#endif
}
__device__ __forceinline__ float fsqrt_(float x) {
#if __has_builtin(__builtin_amdgcn_sqrtf)
    return __builtin_amdgcn_sqrtf(x);
#else
    return sqrtf(x);
#endif
}
__device__ __forceinline__ float frcp_(float x) {
#if __has_builtin(__builtin_amdgcn_rcpf)
    return __builtin_amdgcn_rcpf(x);
#else
    return 1.0f / x;
#endif
}
__device__ __forceinline__ unsigned int pkbf(float lo, float hi) {
    unsigned int a = __builtin_bit_cast(unsigned int, lo) + 0x8000u;
    unsigned int b = __builtin_bit_cast(unsigned int, hi) + 0x8000u;
    return __builtin_amdgcn_perm(b, a, 0x07060302u);
}
__device__ __forceinline__ unsigned short f2b(float f) {
    return (unsigned short)((__builtin_bit_cast(unsigned int, f) + 0x8000u) >> 16);
}

// ---- pre-kernel: fp32 -> bf16 for W (ws[0..W_ELEMS)) and feat (ws[W_ELEMS..)) ----
__global__ __launch_bounds__(256, 8)
void cvt_kernel(const float* __restrict__ feat_g, const float* __restrict__ W_g,
                unsigned short* __restrict__ ws)
{
    int gid = blockIdx.x * 256 + threadIdx.x;           // 8 elems per thread
    const float* src;
    unsigned short* dst;
    if (gid < W_ELEMS/8) {
        src = W_g + gid*8;  dst = ws + gid*8;
    } else {
        int g2 = gid - W_ELEMS/8;                        // < F_ELEMS/8 by grid size
        src = feat_g + g2*8; dst = ws + W_ELEMS + g2*8;
    }
    f32x4 a = *(const f32x4*)src;
    f32x4 b = *(const f32x4*)(src + 4);
    unsigned int o[4] = { pkbf(a[0],a[1]), pkbf(a[2],a[3]), pkbf(b[0],b[1]), pkbf(b[2],b[3]) };
    *(f32x4*)dst = *(f32x4*)o;   // 16B store of 8 bf16
}

__global__ __launch_bounds__(512, 4)
void pgb_kernel(const unsigned short* __restrict__ ws,   // Wbf | featbf
                const float* __restrict__ diff_g,
                const float* __restrict__ mask_g,
                float* __restrict__ out_g)
{
    const unsigned short* Wbf    = ws;
    const unsigned short* featbf = ws + W_ELEMS;

    __shared__ __align__(16) unsigned char smem[SMEM_TOTAL];
    unsigned short* Tt   = (unsigned short*)(smem);      // aliases phi bufs (post-barrier)
    float*          ylds = (float*)(smem + OFF_Y);

    const int t    = threadIdx.x;
    const int b    = blockIdx.x >> 7;
    const int n0   = (blockIdx.x & 127) << 3;
    const int wave = t >> 6;
    const int lane = t & 63;
    const int l15  = lane & 15;
    const int q    = lane >> 4;
    const int wr   = wave >> 1;          // rowgroup: rowtiles 2wr, 2wr+1 (n_local)
    const int ct0  = (wave & 1) << 2;    // colgroup: coltiles ct0..ct0+3 (skip 7)

    // zero feat pad rows 104..111 in both buffers (read by coltile 6's i=104..111)
    {
        unsigned int* p0 = (unsigned int*)(smem + OFF_FEAT0 + DI*PST*2);
        unsigned int* p1 = (unsigned int*)(smem + OFF_FEAT1 + DI*PST*2);
        if (t < 288) { p0[t] = 0u; p1[t] = 0u; }
    }

    f32x4 acc[2][4];
#pragma unroll
    for (int rr = 0; rr < 2; ++rr)
#pragma unroll
        for (int cc = 0; cc < 4; ++cc)
            acc[rr][cc] = (f32x4){0.f, 0.f, 0.f, 0.f};

    // phi thread mapping: 8 n x 2 k-halves x 32 m-pairs
    const int pn = t >> 6;               // n-row 0..7 (== wave)
    const int kh = (t >> 5) & 1;         // k-half: k0 = 8*kh
    const int pm = (t & 31) << 1;        // m pair base (even)
    const float CEXP = -23.083120654223414f;   // -GAMMA * log2(e)
    const float A1   = 6.155498841126244f;     // -2*CEXP*DL
    const float V2   = -0.8207331788168325f;   // 2*CEXP*DL^2
    const float K0OFF = kh ? 1.0666666666666667f : 0.f;       // k0*DL
    const float S0B   = kh ? -6.976232019943076f : -0.41036658940841624f; // A0+V2*k0
    const size_t dmrow = (size_t)((b << 10) + n0 + pn) << 10;

    // feat staging mapping: 832 16B-chunks; thread t -> chunk t (+ chunk 512+t if t<320)
    const int fi0 = t >> 3, part0 = (t & 7) << 3;
    const int fi1 = 64 + (t >> 3);
    const size_t fbase = (size_t)b * DI << 10;

    // ---- prologue: tile 0 registers ----
    float dx0, dy0, dz0, dx1, dy1, dz1, mk0, mk1;
    s16x8 fr0, fr1;
    {
        const float* dp = diff_g + (dmrow + pm)*3;
        dx0=dp[0]; dy0=dp[1]; dz0=dp[2]; dx1=dp[3]; dy1=dp[4]; dz1=dp[5];
        const float* mp = mask_g + dmrow + pm;
        mk0=mp[0]; mk1=mp[1];
        fr0 = *(const s16x8*)(featbf + fbase + ((size_t)fi0 << 10) + part0);
        if (t < 320)
            fr1 = *(const s16x8*)(featbf + fbase + ((size_t)fi1 << 10) + part0);
    }

    for (int s = 0; s < 16; ++s) {
        const int ms = s * MT;
        unsigned short* phibuf  = (unsigned short*)(smem + ((s & 1) ? OFF_PHI1 : OFF_PHI0));
        unsigned short* featbuf = (unsigned short*)(smem + ((s & 1) ? OFF_FEAT1 : OFF_FEAT0));
        // (a) prefetch tile s+1 (diff/mask/feat) — latency covered by (b)+(c)
        float nx0=0, ny0=0, nz0=0, nx1=0, ny1=0, nz1=0, nm0=0, nm1=0;
        s16x8 nf0, nf1;
        if (s < 15) {
            const float* dp = diff_g + (dmrow + ms + MT + pm)*3;
            nx0=dp[0]; ny0=dp[1]; nz0=dp[2]; nx1=dp[3]; ny1=dp[4]; nz1=dp[5];
            const float* mp = mask_g + dmrow + ms + MT + pm;
            nm0=mp[0]; nm1=mp[1];
            nf0 = *(const s16x8*)(featbf + fbase + ((size_t)fi0 << 10) + ms + MT + part0);
            if (t < 320)
                nf1 = *(const s16x8*)(featbf + fbase + ((size_t)fi1 << 10) + ms + MT + part0);
        }
        // (b) phi(s): log-space recurrence, 8 k x 2 m per thread
        {
            float r0 = fsqrt_(fmaf(dx0,dx0, fmaf(dy0,dy0, fmaf(dz0,dz0, 1e-12f))));
            float r1 = fsqrt_(fmaf(dx1,dx1, fmaf(dy1,dy1, fmaf(dz1,dz1, 1e-12f))));
            float t0 = r0 - K0OFF, t1 = r1 - K0OFF;
            float E0 = fmaf(CEXP*t0, t0, flog2(mk0));
            float E1 = fmaf(CEXP*t1, t1, flog2(mk1));
            float s0 = fmaf(A1, r0, S0B);
            float s1 = fmaf(A1, r1, S0B);
            unsigned short* pw = phibuf + (pn*16 + kh*8)*PST + pm;
#pragma unroll
            for (int j = 0; j < 8; ++j) {
                float p0 = fexp2(E0);
                float p1 = fexp2(E1);
                *(unsigned int*)(pw + j*PST) = pkbf(p0, p1);
                E0 += s0; s0 += V2;
                E1 += s1; s1 += V2;
            }
        }
        // (c) feat(s) -> LDS (bf16 passthrough, b128 writes)
        *(s16x8*)(featbuf + fi0*PST + part0) = fr0;
        if (t < 320)
            *(s16x8*)(featbuf + fi1*PST + part0) = fr1;
        // (d) single barrier per iter
        __syncthreads();
        // (e) GEMM1 on tile s
#pragma unroll
        for (int kk = 0; kk < 2; ++kk) {
            const int mo = kk*32 + q*8;
            s16x8 a0 = *(const s16x8*)(phibuf + ((2*wr    )*16 + l15)*PST + mo);
            s16x8 a1 = *(const s16x8*)(phibuf + ((2*wr + 1)*16 + l15)*PST + mo);
#pragma unroll
            for (int cc = 0; cc < 4; ++cc) {
                if (ct0 + cc < 7) {
                    s16x8 bf = *(const s16x8*)(featbuf + ((ct0+cc)*16 + l15)*PST + mo);
                    acc[0][cc] = __builtin_amdgcn_mfma_f32_16x16x32_bf16(a0, bf, acc[0][cc], 0, 0, 0);
                    acc[1][cc] = __builtin_amdgcn_mfma_f32_16x16x32_bf16(a1, bf, acc[1][cc], 0, 0, 0);
                }
            }
        }
        // (f) roll registers
        dx0=nx0; dy0=ny0; dz0=nz0; dx1=nx1; dy1=ny1; dz1=nz1; mk0=nm0; mk1=nm1;
        fr0 = nf0; if (t < 320) fr1 = nf1;
    }

    __syncthreads();   // phi bufs free -> Tt may overwrite

    // ---- acc (C: col=l15=i_local, row=q*4+r=k; tiles (n_local, i-tile)) -> Tt[n][k*104+i]
#pragma unroll
    for (int rr = 0; rr < 2; ++rr) {
        int nloc = 2*wr + rr;
#pragma unroll
        for (int cc = 0; cc < 4; ++cc) {
            int i = (ct0+cc)*16 + l15;
            if (ct0 + cc < 7 && i < DI) {
#pragma unroll
                for (int r = 0; r < 4; ++r)
                    Tt[nloc*TTST + (q*4+r)*DI + i] = f2b(acc[rr][cc][r]);
            }
        }
    }
    __syncthreads();

    // ---- GEMM2: y[o,n] = sum_ki Wbf[k,o,i]*Tt[n][ki]; 52 K-steps of 32 ----
    // B-cols 8..15 duplicate rows 0..7 (broadcast) and are ignored at write.
    f32x4 y0 = (f32x4){0.f,0.f,0.f,0.f}, y1 = (f32x4){0.f,0.f,0.f,0.f};
    const int o0 = wave*16 + l15;
    const int o1 = 128 + l15;            // o-tile 8, wave 0's second acc
#pragma unroll 4
    for (int s3 = 0; s3 < 52; ++s3) {
        int a = s3*4 + q;                // 8-elem ki block; k=a/13, i=(a%13)*8
        int k = a / 13;
        int i = (a - k*13) << 3;
        s16x8 bf = *(const s16x8*)(Tt + (l15 & 7)*TTST + s3*32 + q*8);
        s16x8 af = *(const s16x8*)(Wbf + (size_t)(k*DO + o0)*DI + i);
        y0 = __builtin_amdgcn_mfma_f32_16x16x32_bf16(af, bf, y0, 0, 0, 0);
        if (wave == 0) {
            s16x8 ag = *(const s16x8*)(Wbf + (size_t)(k*DO + o1)*DI + i);
            y1 = __builtin_amdgcn_mfma_f32_16x16x32_bf16(ag, bf, y1, 0, 0, 0);
        }
    }
    if (l15 < 8) {
#pragma unroll
        for (int r = 0; r < 4; ++r)
            ylds[(wave*16 + q*4 + r)*YST + l15] = y0[r];
        if (wave == 0) {
#pragma unroll
            for (int r = 0; r < 4; ++r)
                ylds[(128 + q*4 + r)*YST + l15] = y1[r];
        }
    }
    __syncthreads();

    // ---- gating epilogue: out[b, o(<120), n0+nn] fp32 ----
    const float L2E = 1.4426950408889634f;
    for (int idx = t; idx < 120*8; idx += 512) {
        int o = idx >> 3, nn = idx & 7;
        float y = ylds[o*YST + nn];
        float v;
        if (o < 32) {
            v = fmaxf(y, 0.f);
        } else if (o < 80) {
            float g = ylds[(120 + (o-32)/3)*YST + nn];
            v = y * frcp_(1.f + fexp2(-g*L2E));
        } else {
            float g = ylds[(136 + (o-80)/5)*YST + nn];
            v = y * frcp_(1.f + fexp2(-g*L2E));
        }
        out_g[((size_t)(b*120 + o) << 10) + n0 + nn] = v;
    }
}

extern "C" void kernel_launch(void* const* d_in, const int* in_sizes, int n_in,
                              void* d_out, int out_size, void* d_ws, size_t ws_size,
                              hipStream_t stream) {
    const float* feat = (const float*)d_in[0];  // [4,104,1024] fp32
    const float* diff = (const float*)d_in[1];  // [4,1024,1024,3] fp32
    const float* mask = (const float*)d_in[2];  // [4,1024,1024] fp32
    const float* W    = (const float*)d_in[3];  // [16,144,104] fp32
    float* out = (float*)d_out;                 // [4,120,1024] fp32
    unsigned short* ws = (unsigned short*)d_ws; // Wbf (479 KB) + featbf (852 KB)
    (void)in_sizes; (void)n_in; (void)out_size; (void)ws_size;
    cvt_kernel<<<dim3((W_ELEMS + F_ELEMS)/8/256), dim3(256), 0, stream>>>(feat, W, ws);
    pgb_kernel<<<dim3(512), dim3(512), 0, stream>>>(ws, diff, mask, out);
}